// Round 5
// baseline (184.003 us; speedup 1.0000x reference)
//
#include <hip/hip_runtime.h>
#include <hip/hip_bf16.h>

#define Tt 512
#define Bb 512
#define DV 256
#define DQ 128
#define DH 64
#define CTXN (Tt * DV)  // 131072 floats: context part of d_out

typedef __attribute__((ext_vector_type(8))) short bf16x8;
typedef __attribute__((ext_vector_type(4))) float f32x4;

__device__ __forceinline__ unsigned short f2bf(float x) {
  unsigned u = __float_as_uint(x);
  u += 0x7FFFu + ((u >> 16) & 1u);   // RNE
  return (unsigned short)(u >> 16);
}
__device__ __forceinline__ float bf2f(unsigned short b) {
  return __uint_as_float(((unsigned)b) << 16);
}

// ---- Kernel 0: prep. blocks 0..511: qh[b,h]; blocks 512..575: W1 -> bf16 ----
__global__ void prep_kernel(const float* __restrict__ query,
                            const float* __restrict__ W1,
                            const float* __restrict__ W2,
                            const float* __restrict__ b1,
                            const float* __restrict__ b2,
                            float* __restrict__ qh,
                            unsigned short* __restrict__ w1bf) {
  __shared__ float q[DQ];
  const int blk = blockIdx.x;
  const int h = threadIdx.x;     // 64
  if (blk < Bb) {
    q[h]      = query[blk * DQ + h];
    q[h + 64] = query[blk * DQ + h + 64];
    __syncthreads();
    const float* w2r = W2 + h * DQ;
    float acc = 0.f;
#pragma unroll 8
    for (int k = 0; k < DQ; ++k) acc = fmaf(w2r[k], q[k], acc);
    qh[blk * DH + h] = acc + b1[h] + b2[h];
  } else {
    int base = (blk - Bb) * 256;
#pragma unroll
    for (int k = 0; k < 4; ++k) {
      int i = base + (k << 6) + h;
      w1bf[i] = f2bf(W1[i]);
    }
  }
}

// ---- Kernel 1: FUSED. One pass over values. ----
// grid 512 = (t-tile tt 0..31) x (b-chunk bc 0..15). Block 256 thr = 4 waves.
// Wave wv handles b = bc*32 + wv*8 + i (i<8) for t rows t0..t0+15.
// Per b: GEMM (M=16 t-rows, N=64 h, K=256) -> tanh -> Wv dot -> e^s, then
// num[t][v] += e^s * v (values re-expanded from the bf16 A-frags in regs),
// den[t] += e^s. No max subtraction: |s| <= sum|Wv|+|bv| <= 8.125 -> e^s <= 3383.
// Partials per wave-chunk wc = bc*4+wv (64 of them) -> global, combined later.
__global__ __launch_bounds__(256, 2) void fused_kernel(
    const float* __restrict__ values,
    const unsigned short* __restrict__ w1bf,
    const float* __restrict__ qh,
    const float* __restrict__ Wv,
    const float* __restrict__ bv,
    float* __restrict__ es,       // [Bb][Tt] e^s
    float* __restrict__ num_p,    // [64][Tt][DV]
    float* __restrict__ den_p) {  // [64][Tt]
  __shared__ __align__(16) unsigned short lB[DH * DV];  // 32 KB swizzled W1
  __shared__ float lQh[32 * DH];                        // 8 KB qh for 32 b's
  const int tid = threadIdx.x;
  const int bcid = blockIdx.x & 15;
  const int t0 = (blockIdx.x >> 4) * 16;
  const int bbase = bcid * 32;

  // stage W1 bf16 -> lB, XOR-swizzle byte ^= (row&7)<<4
  const uint4* w1v = (const uint4*)w1bf;
#pragma unroll
  for (int i = 0; i < 8; ++i) {
    int vec = i * 256 + tid;
    uint4 d = w1v[vec];
    int row = vec >> 5;
    int u = vec & 31;
    int byte = (row << 9) + (u << 4);
    *(uint4*)((char*)lB + (byte ^ ((row & 7) << 4))) = d;
  }
  // stage qh rows for this block's 32 b's
#pragma unroll
  for (int i = 0; i < 8; ++i)
    lQh[i * 256 + tid] = qh[bbase * DH + i * 256 + tid];
  __syncthreads();

  const int wv = tid >> 6, lane = tid & 63;
  const int lrow = lane & 15, g = lane >> 4;

  float wvc[4];
#pragma unroll
  for (int nt = 0; nt < 4; ++nt) wvc[nt] = Wv[nt * 16 + lrow];
  const float bv0 = bv[0];

  float num[8][8];
#pragma unroll
  for (int ks = 0; ks < 8; ++ks)
#pragma unroll
    for (int e = 0; e < 8; ++e) num[ks][e] = 0.f;
  float den = 0.f;

#pragma unroll 2
  for (int i = 0; i < 8; ++i) {
    const int b = bbase + wv * 8 + i;
    const float* ap = values + ((size_t)b * Tt + t0 + lrow) * DV + g * 8;

    // load + pack A fragments: row t0+lrow, v = ks*32 + g*8 + e
    bf16x8 af[8];
#pragma unroll
    for (int ks = 0; ks < 8; ++ks) {
      float4 f0 = *(const float4*)(ap + ks * 32);
      float4 f1 = *(const float4*)(ap + ks * 32 + 4);
      af[ks][0] = (short)f2bf(f0.x); af[ks][1] = (short)f2bf(f0.y);
      af[ks][2] = (short)f2bf(f0.z); af[ks][3] = (short)f2bf(f0.w);
      af[ks][4] = (short)f2bf(f1.x); af[ks][5] = (short)f2bf(f1.y);
      af[ks][6] = (short)f2bf(f1.z); af[ks][7] = (short)f2bf(f1.w);
    }

    // GEMM: M=16 (t-rows), N=64 (4 n-tiles), K=256
    f32x4 acc[4];
#pragma unroll
    for (int nt = 0; nt < 4; ++nt) acc[nt] = (f32x4){0.f, 0.f, 0.f, 0.f};
#pragma unroll
    for (int ks = 0; ks < 8; ++ks) {
      int k2 = (ks * 32 + g * 8) * 2;
#pragma unroll
      for (int nt = 0; nt < 4; ++nt) {
        int brow = nt * 16 + lrow;
        bf16x8 bf = *(const bf16x8*)((const char*)lB +
                                     (((brow << 9) + k2) ^ ((brow & 7) << 4)));
        acc[nt] = __builtin_amdgcn_mfma_f32_16x16x32_bf16(af[ks], bf, acc[nt], 0, 0, 0);
      }
    }

    // epilogue: +qh, tanh, *Wv, reduce 64 cols -> s for 16 rows
    const float* qrow = lQh + (wv * 8 + i) * DH;
    float sc[4] = {0.f, 0.f, 0.f, 0.f};
#pragma unroll
    for (int nt = 0; nt < 4; ++nt) {
      float qv = qrow[nt * 16 + lrow];
#pragma unroll
      for (int j = 0; j < 4; ++j) {
        float hv = acc[nt][j] + qv;
        float e2 = __expf(2.f * hv);
        float th = (e2 - 1.f) / (e2 + 1.f);
        sc[j] = fmaf(th, wvc[nt], sc[j]);
      }
    }
#pragma unroll
    for (int j = 0; j < 4; ++j) {
      float v = sc[j];
      v += __shfl_xor(v, 1);
      v += __shfl_xor(v, 2);
      v += __shfl_xor(v, 4);
      v += __shfl_xor(v, 8);
      sc[j] = __expf(v + bv0);   // e^{s[row g*4+j]}, uniform across 16-lane group
    }
    // write e^s (4 lanes: lrow==0), rows t0+g*4+j -> 64B contiguous per b
    if (lrow == 0) {
#pragma unroll
      for (int j = 0; j < 4; ++j)
        es[(size_t)b * Tt + t0 + g * 4 + j] = sc[j];
    }
    // broadcast w for this lane's row (t = lrow): held in group lrow>>2, reg lrow&3
    int src = (lrow >> 2) << 4;
    float w0 = __shfl(sc[0], src), w1 = __shfl(sc[1], src);
    float w2 = __shfl(sc[2], src), w3 = __shfl(sc[3], src);
    int jm = lrow & 3;
    float w = (jm == 0) ? w0 : (jm == 1) ? w1 : (jm == 2) ? w2 : w3;
    den += w;   // g-redundant; written from g==0 only
#pragma unroll
    for (int ks = 0; ks < 8; ++ks)
#pragma unroll
      for (int e = 0; e < 8; ++e)
        num[ks][e] = fmaf(w, bf2f((unsigned short)af[ks][e]), num[ks][e]);
  }

  // write per-wave partials (wc = bcid*4+wv), layout [wc][t][v]
  const int wc = bcid * 4 + wv;
  float* np = num_p + ((size_t)wc * Tt + t0 + lrow) * DV + g * 8;
#pragma unroll
  for (int ks = 0; ks < 8; ++ks) {
    *(float4*)(np + ks * 32) =
        make_float4(num[ks][0], num[ks][1], num[ks][2], num[ks][3]);
    *(float4*)(np + ks * 32 + 4) =
        make_float4(num[ks][4], num[ks][5], num[ks][6], num[ks][7]);
  }
  if (g == 0) den_p[wc * Tt + t0 + lrow] = den;
}

// ---- Kernel 2: combine partials -> context[t,:], and Z[t] ----
__global__ __launch_bounds__(256) void fin_ctx_kernel(
    const float* __restrict__ num_p, const float* __restrict__ den_p,
    float* __restrict__ Zbuf, float* __restrict__ out) {
  const int t = blockIdx.x;
  const int tid = threadIdx.x;
  float Z = 0.f;
#pragma unroll 16
  for (int w = 0; w < 64; ++w) Z += den_p[w * Tt + t];   // uniform -> scalar loads
  float s = 0.f;
#pragma unroll 8
  for (int w = 0; w < 64; ++w)
    s += num_p[((size_t)w * Tt + t) * DV + tid];
  out[t * DV + tid] = s / Z;
  if (tid == 0) Zbuf[t] = Z;
}

// ---- Kernel 3: weights[b,t] = e^s / Z[t] ----
__global__ __launch_bounds__(256) void fin_w_kernel(
    const float* __restrict__ es, const float* __restrict__ Zbuf,
    float* __restrict__ out) {
  const int b = blockIdx.x;
  const int tid = threadIdx.x;
#pragma unroll
  for (int i = 0; i < 2; ++i) {
    int t = i * 256 + tid;
    out[CTXN + b * Tt + t] = es[(size_t)b * Tt + t] / Zbuf[t];
  }
}

extern "C" void kernel_launch(void* const* d_in, const int* in_sizes, int n_in,
                              void* d_out, int out_size, void* d_ws, size_t ws_size,
                              hipStream_t stream) {
  const float* query  = (const float*)d_in[0];
  const float* values = (const float*)d_in[1];
  const float* W1     = (const float*)d_in[2];
  const float* b1     = (const float*)d_in[3];
  const float* W2     = (const float*)d_in[4];
  const float* b2     = (const float*)d_in[5];
  const float* Wv     = (const float*)d_in[6];
  const float* bv     = (const float*)d_in[7];
  float* out = (float*)d_out;
  char* ws = (char*)d_ws;
  float* qh            = (float*)ws;                       // 128 KiB
  unsigned short* w1bf = (unsigned short*)(ws + 131072);   //  32 KiB
  float* es            = (float*)(ws + 163840);            //   1 MiB
  float* den_p         = (float*)(ws + 1212416);           // 128 KiB
  float* Zbuf          = (float*)(ws + 1343488);           //   2 KiB
  float* num_p         = (float*)(ws + 1345536);           //  32 MiB

  prep_kernel<<<dim3(Bb + 64), dim3(64), 0, stream>>>(query, W1, W2, b1, b2, qh, w1bf);
  fused_kernel<<<dim3(512), dim3(256), 0, stream>>>(values, w1bf, qh, Wv, bv,
                                                    es, num_p, den_p);
  fin_ctx_kernel<<<dim3(Tt), dim3(256), 0, stream>>>(num_p, den_p, Zbuf, out);
  fin_w_kernel<<<dim3(Bb), dim3(256), 0, stream>>>(es, Zbuf, out);
}

// Round 6
// 134.846 us; speedup vs baseline: 1.3645x; 1.3645x over previous
//
#include <hip/hip_runtime.h>
#include <hip/hip_bf16.h>

#define Tt 512
#define Bb 512
#define DV 256
#define DQ 128
#define DH 64
#define CTXN (Tt * DV)  // 131072 floats: context part of d_out
#define TT 16           // t-rows per block
#define BCH 16          // b's per block (chunk)
#define NCH (Bb / BCH)  // 32 chunks

typedef __attribute__((ext_vector_type(8))) short bf16x8;
typedef __attribute__((ext_vector_type(4))) float f32x4;

__device__ __forceinline__ unsigned short f2bf(float x) {
  unsigned u = __float_as_uint(x);
  u += 0x7FFFu + ((u >> 16) & 1u);   // RNE
  return (unsigned short)(u >> 16);
}

// ---- Kernel 0: prep. blocks 0..511: qh[b,h]; blocks 512..575: W1 -> bf16 ----
__global__ void prep_kernel(const float* __restrict__ query,
                            const float* __restrict__ W1,
                            const float* __restrict__ W2,
                            const float* __restrict__ b1,
                            const float* __restrict__ b2,
                            float* __restrict__ qh,
                            unsigned short* __restrict__ w1bf) {
  __shared__ float q[DQ];
  const int blk = blockIdx.x;
  const int h = threadIdx.x;     // 64
  if (blk < Bb) {
    q[h]      = query[blk * DQ + h];
    q[h + 64] = query[blk * DQ + h + 64];
    __syncthreads();
    const float* w2r = W2 + h * DQ;
    float acc = 0.f;
#pragma unroll 8
    for (int k = 0; k < DQ; ++k) acc = fmaf(w2r[k], q[k], acc);
    qh[blk * DH + h] = acc + b1[h] + b2[h];
  } else {
    int base = (blk - Bb) * 256;
#pragma unroll
    for (int k = 0; k < 4; ++k) {
      int i = base + (k << 6) + h;
      w1bf[i] = f2bf(W1[i]);
    }
  }
}

// ---- Kernel 1: FUSED, phase-interleaved. One HBM pass over values. ----
// grid 1024 = (t-tile 0..31) x (chunk 0..31). Block 256 thr = 4 waves.
// Per bg-iter (4 of them):
//   Phase A: wave wv scores b = b0+bg*4+wv (GEMM M=16,N=64,K=256 -> tanh ->
//            Wv-dot -> e^s), A-frags TRANSIENT per ks (no big register state).
//            e^s -> LDS wlds[bg&1] (+ global es). One barrier.
//   Phase B: all waves re-read those 4 b's values rows (L2/L3-hot, lag = one
//            phase) for their v-slice; num[16] += e^s * v; den += e^s.
// No max subtraction: |s| <= sum|Wv|+|bv| <= 8.125 -> e^s <= 3383 (f32 safe).
__global__ __launch_bounds__(256, 4) void fused2_kernel(
    const float* __restrict__ values,
    const unsigned short* __restrict__ w1bf,
    const float* __restrict__ qh,
    const float* __restrict__ Wv,
    const float* __restrict__ bv,
    float* __restrict__ es,       // [Bb][Tt]
    float* __restrict__ num_p,    // [NCH][Tt][DV]
    float* __restrict__ den_p) {  // [NCH][Tt]
  __shared__ __align__(16) unsigned short lB[DH * DV];  // 32 KB swizzled W1
  __shared__ float lQh[BCH * DH];                       // 4 KB
  __shared__ float wlds[2][4][TT];                      // 512 B, double-buffered
  const int tid = threadIdx.x;
  const int chunk = blockIdx.x & 31;
  const int t0 = (blockIdx.x >> 5) * TT;
  const int b0 = chunk * BCH;

  // stage W1 bf16 -> lB, XOR-swizzle byte ^= (row&7)<<4
  const uint4* w1v = (const uint4*)w1bf;
#pragma unroll
  for (int i = 0; i < 8; ++i) {
    int vec = i * 256 + tid;
    uint4 d = w1v[vec];
    int row = vec >> 5;
    int u = vec & 31;
    int byte = (row << 9) + (u << 4);
    *(uint4*)((char*)lB + (byte ^ ((row & 7) << 4))) = d;
  }
#pragma unroll
  for (int i = 0; i < 4; ++i)
    lQh[i * 256 + tid] = qh[b0 * DH + i * 256 + tid];
  __syncthreads();

  const int wv = tid >> 6, lane = tid & 63;
  const int lrow = lane & 15, g = lane >> 4;
  // phase-B mapping: lane -> (t=bt, v-slice v0..v0+15)
  const int bt = lane & 15;
  const int bq = lane >> 4;
  const int v0 = wv * 64 + bq * 16;

  float wvc[4];
#pragma unroll
  for (int nt = 0; nt < 4; ++nt) wvc[nt] = Wv[nt * 16 + lrow];
  const float bv0 = bv[0];

  float num[16];
#pragma unroll
  for (int e = 0; e < 16; ++e) num[e] = 0.f;
  float den = 0.f;

#pragma unroll
  for (int bg = 0; bg < 4; ++bg) {
    // ---------- Phase A: this wave's b ----------
    const int b = b0 + bg * 4 + wv;
    const float* ap = values + ((size_t)b * Tt + t0 + lrow) * DV + g * 8;

    f32x4 acc[4];
#pragma unroll
    for (int nt = 0; nt < 4; ++nt) acc[nt] = (f32x4){0.f, 0.f, 0.f, 0.f};
#pragma unroll
    for (int ks = 0; ks < 8; ++ks) {
      float4 f0 = *(const float4*)(ap + ks * 32);
      float4 f1 = *(const float4*)(ap + ks * 32 + 4);
      bf16x8 af;
      af[0] = (short)f2bf(f0.x); af[1] = (short)f2bf(f0.y);
      af[2] = (short)f2bf(f0.z); af[3] = (short)f2bf(f0.w);
      af[4] = (short)f2bf(f1.x); af[5] = (short)f2bf(f1.y);
      af[6] = (short)f2bf(f1.z); af[7] = (short)f2bf(f1.w);
      int k2 = (ks * 32 + g * 8) * 2;
#pragma unroll
      for (int nt = 0; nt < 4; ++nt) {
        int brow = nt * 16 + lrow;
        bf16x8 bf = *(const bf16x8*)((const char*)lB +
                                     (((brow << 9) + k2) ^ ((brow & 7) << 4)));
        acc[nt] = __builtin_amdgcn_mfma_f32_16x16x32_bf16(af, bf, acc[nt], 0, 0, 0);
      }
    }

    // epilogue: +qh, tanh, *Wv, 16-lane reduce -> e^s for rows t0+g*4+j
    const float* qrow = lQh + (bg * 4 + wv) * DH;
    float sc[4] = {0.f, 0.f, 0.f, 0.f};
#pragma unroll
    for (int nt = 0; nt < 4; ++nt) {
      float qv = qrow[nt * 16 + lrow];
#pragma unroll
      for (int j = 0; j < 4; ++j) {
        float hv = acc[nt][j] + qv;
        float e2 = __expf(2.f * hv);
        float th = (e2 - 1.f) / (e2 + 1.f);
        sc[j] = fmaf(th, wvc[nt], sc[j]);
      }
    }
#pragma unroll
    for (int j = 0; j < 4; ++j) {
      float v = sc[j];
      v += __shfl_xor(v, 1);
      v += __shfl_xor(v, 2);
      v += __shfl_xor(v, 4);
      v += __shfl_xor(v, 8);
      sc[j] = __expf(v + bv0);
    }
    if (lrow == 0) {
#pragma unroll
      for (int j = 0; j < 4; ++j) {
        wlds[bg & 1][wv][g * 4 + j] = sc[j];
        es[(size_t)b * Tt + t0 + g * 4 + j] = sc[j];
      }
    }
    __syncthreads();

    // ---------- Phase B: 4 b's, this wave's v-slice (cache-hot re-read) ----
#pragma unroll
    for (int bl = 0; bl < 4; ++bl) {
      const int bb = b0 + bg * 4 + bl;
      const float* p = values + ((size_t)bb * Tt + t0 + bt) * DV + v0;
      float4 x0 = ((const float4*)p)[0];
      float4 x1 = ((const float4*)p)[1];
      float4 x2 = ((const float4*)p)[2];
      float4 x3 = ((const float4*)p)[3];
      float w = wlds[bg & 1][bl][bt];
      den += w;
      num[ 0] = fmaf(w, x0.x, num[ 0]); num[ 1] = fmaf(w, x0.y, num[ 1]);
      num[ 2] = fmaf(w, x0.z, num[ 2]); num[ 3] = fmaf(w, x0.w, num[ 3]);
      num[ 4] = fmaf(w, x1.x, num[ 4]); num[ 5] = fmaf(w, x1.y, num[ 5]);
      num[ 6] = fmaf(w, x1.z, num[ 6]); num[ 7] = fmaf(w, x1.w, num[ 7]);
      num[ 8] = fmaf(w, x2.x, num[ 8]); num[ 9] = fmaf(w, x2.y, num[ 9]);
      num[10] = fmaf(w, x2.z, num[10]); num[11] = fmaf(w, x2.w, num[11]);
      num[12] = fmaf(w, x3.x, num[12]); num[13] = fmaf(w, x3.y, num[13]);
      num[14] = fmaf(w, x3.z, num[14]); num[15] = fmaf(w, x3.w, num[15]);
    }
    // no second barrier needed: next A writes wlds[(bg+1)&1]; the barrier in
    // the next iteration orders B(bg) reads vs A(bg+2) overwrites.
  }

  // write partials: num_p[chunk][t0+bt][v0..v0+15], den_p[chunk][t0+bt]
  float* np = num_p + ((size_t)chunk * Tt + t0 + bt) * DV + v0;
  ((float4*)np)[0] = make_float4(num[ 0], num[ 1], num[ 2], num[ 3]);
  ((float4*)np)[1] = make_float4(num[ 4], num[ 5], num[ 6], num[ 7]);
  ((float4*)np)[2] = make_float4(num[ 8], num[ 9], num[10], num[11]);
  ((float4*)np)[3] = make_float4(num[12], num[13], num[14], num[15]);
  if (wv == 0 && bq == 0) den_p[chunk * Tt + t0 + bt] = den;
}

// ---- Kernel 2: combine partials -> context[t,:], and Z[t] ----
__global__ __launch_bounds__(256) void fin_ctx_kernel(
    const float* __restrict__ num_p, const float* __restrict__ den_p,
    float* __restrict__ Zbuf, float* __restrict__ out) {
  const int t = blockIdx.x;
  const int tid = threadIdx.x;
  float Z = 0.f;
#pragma unroll 8
  for (int c = 0; c < NCH; ++c) Z += den_p[c * Tt + t];
  float s = 0.f;
#pragma unroll 8
  for (int c = 0; c < NCH; ++c)
    s += num_p[((size_t)c * Tt + t) * DV + tid];
  out[t * DV + tid] = s / Z;
  if (tid == 0) Zbuf[t] = Z;
}

// ---- Kernel 3: weights[b,t] = e^s / Z[t] ----
__global__ __launch_bounds__(256) void fin_w_kernel(
    const float* __restrict__ es, const float* __restrict__ Zbuf,
    float* __restrict__ out) {
  const int b = blockIdx.x;
  const int tid = threadIdx.x;
#pragma unroll
  for (int i = 0; i < 2; ++i) {
    int t = i * 256 + tid;
    out[CTXN + b * Tt + t] = es[(size_t)b * Tt + t] / Zbuf[t];
  }
}

extern "C" void kernel_launch(void* const* d_in, const int* in_sizes, int n_in,
                              void* d_out, int out_size, void* d_ws, size_t ws_size,
                              hipStream_t stream) {
  const float* query  = (const float*)d_in[0];
  const float* values = (const float*)d_in[1];
  const float* W1     = (const float*)d_in[2];
  const float* b1     = (const float*)d_in[3];
  const float* W2     = (const float*)d_in[4];
  const float* b2     = (const float*)d_in[5];
  const float* Wv     = (const float*)d_in[6];
  const float* bv     = (const float*)d_in[7];
  float* out = (float*)d_out;
  char* ws = (char*)d_ws;
  float* qh            = (float*)ws;                       // 128 KiB
  unsigned short* w1bf = (unsigned short*)(ws + 131072);   //  32 KiB
  float* es            = (float*)(ws + 163840);            //   1 MiB
  float* den_p         = (float*)(ws + 1212416);           //  64 KiB
  float* Zbuf          = (float*)(ws + 1277952);           //   2 KiB
  float* num_p         = (float*)(ws + 1280000);           //  16 MiB

  prep_kernel<<<dim3(Bb + 64), dim3(64), 0, stream>>>(query, W1, W2, b1, b2, qh, w1bf);
  fused2_kernel<<<dim3(1024), dim3(256), 0, stream>>>(values, w1bf, qh, Wv, bv,
                                                      es, num_p, den_p);
  fin_ctx_kernel<<<dim3(Tt), dim3(256), 0, stream>>>(num_p, den_p, Zbuf, out);
  fin_w_kernel<<<dim3(Bb), dim3(256), 0, stream>>>(es, Zbuf, out);
}

// Round 7
// 111.714 us; speedup vs baseline: 1.6471x; 1.2071x over previous
//
#include <hip/hip_runtime.h>
#include <hip/hip_bf16.h>

#define Tt 512
#define Bb 512
#define DV 256
#define DQ 128
#define DH 64
#define CTXN (Tt * DV)  // 131072 floats: context part of d_out
#define VBF_BYTES ((size_t)Bb * Tt * DV * 2)  // 128 MiB bf16 copy of values, [b][t][v]

typedef __attribute__((ext_vector_type(8))) short bf16x8;
typedef __attribute__((ext_vector_type(8))) unsigned short u16x8;
typedef __attribute__((ext_vector_type(4))) float f32x4;

__device__ __forceinline__ unsigned short f2bf(float x) {
  unsigned u = __float_as_uint(x);
  u += 0x7FFFu + ((u >> 16) & 1u);   // RNE
  return (unsigned short)(u >> 16);
}
__device__ __forceinline__ float bf2f(unsigned short b) {
  return __uint_as_float(((unsigned)b) << 16);
}

// ---- Kernel 0: prep. blocks 0..511: qh[b,h]; blocks 512..575: W1 -> bf16 ----
__global__ void prep_kernel(const float* __restrict__ query,
                            const float* __restrict__ W1,
                            const float* __restrict__ W2,
                            const float* __restrict__ b1,
                            const float* __restrict__ b2,
                            float* __restrict__ qh,
                            unsigned short* __restrict__ w1bf) {
  __shared__ float q[DQ];
  const int blk = blockIdx.x;
  const int h = threadIdx.x;     // 64
  if (blk < Bb) {
    q[h]      = query[blk * DQ + h];
    q[h + 64] = query[blk * DQ + h + 64];
    __syncthreads();
    const float* w2r = W2 + h * DQ;
    float acc = 0.f;
#pragma unroll 8
    for (int k = 0; k < DQ; ++k) acc = fmaf(w2r[k], q[k], acc);
    qh[blk * DH + h] = acc + b1[h] + b2[h];
  } else {
    int base = (blk - Bb) * 256;
#pragma unroll
    for (int k = 0; k < 4; ++k) {
      int i = base + (k << 6) + h;
      w1bf[i] = f2bf(W1[i]);
    }
  }
}

// ---- Kernel 1: scores -> e^s, plus bf16 copy of values in SAME layout ----
// Block = 64 rows (one b, 64 consecutive t). Barrier-free main loop (round-3
// structure, proven ~6 TB/s). No max subtraction needed: |s| <= 8.125.
// esT[t*512 + b] = e^s ; vbf[b][t][v] coalesced (template WRITEV for fallback).
template <bool WRITEV>
__global__ __launch_bounds__(256, 4) void score2_kernel(
    const float* __restrict__ values,
    const unsigned short* __restrict__ w1bf,
    const float* __restrict__ qh,
    const float* __restrict__ Wv,
    const float* __restrict__ bv,
    float* __restrict__ esT,
    unsigned short* __restrict__ vbf) {
  __shared__ __align__(16) unsigned short lB[DH * DV];  // 32 KB, swizzled bf16
  const int tid = threadIdx.x;
  const int m0 = blockIdx.x * 64;
  const int bidx = m0 >> 9;       // all 64 rows share the same b (64 | 512)

  // stage W1 bf16 -> lB (16B units), XOR-swizzle byte ^= (row&7)<<4
  const uint4* w1v = (const uint4*)w1bf;
#pragma unroll
  for (int i = 0; i < 8; ++i) {
    int vec = i * 256 + tid;        // 2048 units of 16B
    uint4 d = w1v[vec];
    int row = vec >> 5;             // 32 units per 256-elem row
    int u = vec & 31;
    int byte = (row << 9) + (u << 4);
    *(uint4*)((char*)lB + (byte ^ ((row & 7) << 4))) = d;
  }
  __syncthreads();

  const int wv = tid >> 6;        // wave 0..3 -> A rows 16*wv .. +15
  const int lane = tid & 63;
  const int lrow = lane & 15;
  const int g = lane >> 4;        // k-group

  f32x4 acc[4];
#pragma unroll
  for (int nt = 0; nt < 4; ++nt) acc[nt] = (f32x4){0.f, 0.f, 0.f, 0.f};

  const int arow = wv * 16 + lrow;
  const float* ap = values + (size_t)(m0 + arow) * DV;
  unsigned short* vst = WRITEV
      ? vbf + (size_t)(m0 + arow) * DV + g * 8   // same layout as the load
      : nullptr;

#pragma unroll
  for (int ks = 0; ks < 8; ++ks) {
    // lane's A fragment: row arow, elements ks*32 + g*8 .. +7 (f32 -> bf16)
    const float* fp = ap + ks * 32 + g * 8;
    float4 f0 = *(const float4*)(fp);
    float4 f1 = *(const float4*)(fp + 4);
    bf16x8 af;
    af[0] = (short)f2bf(f0.x); af[1] = (short)f2bf(f0.y);
    af[2] = (short)f2bf(f0.z); af[3] = (short)f2bf(f0.w);
    af[4] = (short)f2bf(f1.x); af[5] = (short)f2bf(f1.y);
    af[6] = (short)f2bf(f1.z); af[7] = (short)f2bf(f1.w);
    if (WRITEV) *(bf16x8*)(vst + ks * 32) = af;  // coalesced: matches load addr
    int k2 = (ks * 32 + g * 8) * 2;  // byte offset of k within a B row
#pragma unroll
    for (int nt = 0; nt < 4; ++nt) {
      int brow = nt * 16 + lrow;
      bf16x8 bf = *(const bf16x8*)((const char*)lB +
                                   (((brow << 9) + k2) ^ ((brow & 7) << 4)));
      acc[nt] = __builtin_amdgcn_mfma_f32_16x16x32_bf16(af, bf, acc[nt], 0, 0, 0);
    }
  }

  // epilogue: h + qh -> tanh -> * Wv, reduce over 64 cols -> e^s
  float bv0 = bv[0];
  float sc[4] = {0.f, 0.f, 0.f, 0.f};
#pragma unroll
  for (int nt = 0; nt < 4; ++nt) {
    int col = nt * 16 + lrow;
    float qv = qh[bidx * DH + col];
    float wvc = Wv[col];
#pragma unroll
    for (int j = 0; j < 4; ++j) {
      float hv = acc[nt][j] + qv;
      float e = __expf(2.f * hv);
      float th = (e - 1.f) / (e + 1.f);
      sc[j] = fmaf(th, wvc, sc[j]);
    }
  }
#pragma unroll
  for (int j = 0; j < 4; ++j) {
    float v = sc[j];
    v += __shfl_xor(v, 1);
    v += __shfl_xor(v, 2);
    v += __shfl_xor(v, 4);
    v += __shfl_xor(v, 8);
    sc[j] = v;
  }
  if (lrow == 0) {
#pragma unroll
    for (int j = 0; j < 4; ++j) {
      int m = m0 + wv * 16 + g * 4 + j;
      int tt = m & (Tt - 1);
      esT[tt * Bb + bidx] = __expf(sc[j] + bv0);   // e^s, bounded by e^8.125
    }
  }
}

// ---- Kernel 2: per-t Z + weights + context, reading bf16 copy (or f32) ----
__global__ __launch_bounds__(1024, 2) void ctx2_kernel(
    const float* __restrict__ values,
    const unsigned short* __restrict__ vbf,
    const float* __restrict__ esT,
    int use_bf,
    float* __restrict__ out) {
  const int t = blockIdx.x;
  const int tid = threadIdx.x;
  const int wv = tid >> 6, lane = tid & 63;
  __shared__ float wbuf[Bb];           // e^s (unnormalized)
  __shared__ float ssum[16];
  __shared__ float red[32][DV];        // 32 KB

  float es = (tid < Bb) ? esT[t * Bb + tid] : 0.f;   // contiguous 2 KB
  float zs = es;
#pragma unroll
  for (int d = 1; d < 64; d <<= 1) zs += __shfl_xor(zs, d);
  if (lane == 0) ssum[wv] = zs;
  if (tid < Bb) wbuf[tid] = es;
  __syncthreads();
  float Z = 0.f;
#pragma unroll
  for (int i = 0; i < 16; ++i) Z += ssum[i];
  const float invZ = 1.f / Z;
  if (tid < Bb)
    out[CTXN + tid * Tt + t] = es * invZ;   // attention_weights[b,t]

  // context[t,:] = (1/Z) * sum_b e^s[b] * v[b,t,:]
  const int unit = tid & 31;   // 8-elem v-slice
  const int brow = tid >> 5;   // 0..31
  float av[8] = {0.f, 0.f, 0.f, 0.f, 0.f, 0.f, 0.f, 0.f};
#pragma unroll 4
  for (int i = 0; i < 16; ++i) {
    int b = (i << 5) + brow;
    float w = wbuf[b];
    if (use_bf) {
      u16x8 v = *(const u16x8*)(vbf + ((size_t)b * Tt + t) * DV + unit * 8);
#pragma unroll
      for (int j = 0; j < 8; ++j) av[j] = fmaf(w, bf2f(v[j]), av[j]);
    } else {
      const float* p = values + ((size_t)b * Tt + t) * DV + unit * 8;
      float4 a = ((const float4*)p)[0];
      float4 c = ((const float4*)p)[1];
      av[0] = fmaf(w, a.x, av[0]); av[1] = fmaf(w, a.y, av[1]);
      av[2] = fmaf(w, a.z, av[2]); av[3] = fmaf(w, a.w, av[3]);
      av[4] = fmaf(w, c.x, av[4]); av[5] = fmaf(w, c.y, av[5]);
      av[6] = fmaf(w, c.z, av[6]); av[7] = fmaf(w, c.w, av[7]);
    }
  }
#pragma unroll
  for (int j = 0; j < 8; ++j) red[brow][unit * 8 + j] = av[j];
  __syncthreads();
  if (tid < DV) {
    float tot = 0.f;
#pragma unroll
    for (int b = 0; b < 32; ++b) tot += red[b][tid];
    out[t * DV + tid] = tot * invZ;
  }
}

extern "C" void kernel_launch(void* const* d_in, const int* in_sizes, int n_in,
                              void* d_out, int out_size, void* d_ws, size_t ws_size,
                              hipStream_t stream) {
  const float* query  = (const float*)d_in[0];
  const float* values = (const float*)d_in[1];
  const float* W1     = (const float*)d_in[2];
  const float* b1     = (const float*)d_in[3];
  const float* W2     = (const float*)d_in[4];
  const float* b2     = (const float*)d_in[5];
  const float* Wv     = (const float*)d_in[6];
  const float* bv     = (const float*)d_in[7];
  float* out = (float*)d_out;
  char* ws = (char*)d_ws;
  float* qh            = (float*)ws;                       // 128 KiB
  unsigned short* w1bf = (unsigned short*)(ws + 131072);   //  32 KiB
  float* esT           = (float*)(ws + 163840);            //   1 MiB
  unsigned short* vbf  = (unsigned short*)(ws + (size_t)2 * 1024 * 1024);
  const bool use_bf = ws_size >= (size_t)2 * 1024 * 1024 + VBF_BYTES;

  prep_kernel<<<dim3(Bb + 64), dim3(64), 0, stream>>>(query, W1, W2, b1, b2, qh, w1bf);
  if (use_bf) {
    score2_kernel<true><<<dim3((Bb * Tt) / 64), dim3(256), 0, stream>>>(
        values, w1bf, qh, Wv, bv, esT, vbf);
    ctx2_kernel<<<dim3(Tt), dim3(1024), 0, stream>>>(values, vbf, esT, 1, out);
  } else {
    score2_kernel<false><<<dim3((Bb * Tt) / 64), dim3(256), 0, stream>>>(
        values, w1bf, qh, Wv, bv, esT, nullptr);
    ctx2_kernel<<<dim3(Tt), dim3(1024), 0, stream>>>(values, nullptr, esT, 0, out);
  }
}